// Round 1
// baseline (833.827 us; speedup 1.0000x reference)
//
#include <hip/hip_runtime.h>

#define BB 32
#define NN 512
#define HH 512
constexpr float QK_SCALE = 0.04419417382415922f; // 1/sqrt(512)

using bf16x8 = __attribute__((ext_vector_type(8))) short;
using f32x4  = __attribute__((ext_vector_type(4))) float;

// fp32 -> bf16 round-to-nearest-even (inputs are finite; no NaN path needed)
__device__ __forceinline__ short f2bf(float f) {
  unsigned int u = __float_as_uint(f);
  unsigned int r = (u + 0x7FFFu + ((u >> 16) & 1u)) >> 16;
  return (short)r;
}

// ---------------------------------------------------------------------------
// prep_x: x fp32 [B][N][H] -> xbf bf16 (same layout) and xT bf16 [B][H][N]
// ---------------------------------------------------------------------------
__global__ __launch_bounds__(256) void prep_x(const float* __restrict__ x,
                                              short* __restrict__ xbf,
                                              short* __restrict__ xT) {
  __shared__ float tile[32][33];
  const int b = blockIdx.z;
  const int n0 = blockIdx.y * 32, h0 = blockIdx.x * 32;
  const int t = threadIdx.x;
  const int i = t >> 3;          // 0..31
  const int j4 = (t & 7) * 4;    // 0,4,...,28
  const float4 v = *(const float4*)&x[((long)b * NN + n0 + i) * HH + h0 + j4];
  short o[4] = {f2bf(v.x), f2bf(v.y), f2bf(v.z), f2bf(v.w)};
  *(uint2*)&xbf[((long)b * NN + n0 + i) * HH + h0 + j4] = *(uint2*)o;
  tile[i][j4 + 0] = v.x; tile[i][j4 + 1] = v.y;
  tile[i][j4 + 2] = v.z; tile[i][j4 + 3] = v.w;
  __syncthreads();
  short p[4] = {f2bf(tile[j4 + 0][i]), f2bf(tile[j4 + 1][i]),
                f2bf(tile[j4 + 2][i]), f2bf(tile[j4 + 3][i])};
  *(uint2*)&xT[((long)b * HH + h0 + i) * NN + n0 + j4] = *(uint2*)p;
}

// ---------------------------------------------------------------------------
// prep_w: Wq/Wk fp32 [H][D] -> Wqt/Wkt bf16 [D][H]  (blockIdx.z selects q/k)
// ---------------------------------------------------------------------------
__global__ __launch_bounds__(256) void prep_w(const float* __restrict__ Wq,
                                              const float* __restrict__ Wk,
                                              short* __restrict__ Wqt,
                                              short* __restrict__ Wkt) {
  __shared__ float tile[32][33];
  const float* W = blockIdx.z ? Wk : Wq;
  short* Wt = blockIdx.z ? Wkt : Wqt;
  const int h0 = blockIdx.y * 32, d0 = blockIdx.x * 32;
  const int t = threadIdx.x;
  const int i = t >> 3;
  const int j4 = (t & 7) * 4;
  const float4 v = *(const float4*)&W[(long)(h0 + i) * HH + d0 + j4];
  tile[i][j4 + 0] = v.x; tile[i][j4 + 1] = v.y;
  tile[i][j4 + 2] = v.z; tile[i][j4 + 3] = v.w;
  __syncthreads();
  short p[4] = {f2bf(tile[j4 + 0][i]), f2bf(tile[j4 + 1][i]),
                f2bf(tile[j4 + 2][i]), f2bf(tile[j4 + 3][i])};
  *(uint2*)&Wt[(long)(d0 + i) * HH + h0 + j4] = *(uint2*)p;
}

// ---------------------------------------------------------------------------
// gemm_bt: C[M][Nc] = A[M][K] * Bt[N][K]^T  (bf16 in, fp32 acc)
// epilogue: v = acc*scale + bias[col]; write bf16 or fp32
// 64x64 tile, BK=64, 4 waves: wave w owns 16-row strip x 64 cols
// ---------------------------------------------------------------------------
template <int WRITE_BF16>
__global__ __launch_bounds__(256) void gemm_bt(const short* __restrict__ A,
                                               const short* __restrict__ Bt,
                                               void* __restrict__ Cv,
                                               const float* __restrict__ bias,
                                               float scale, int M, int Nc, int K,
                                               long sA, long sB, long sC) {
  __shared__ short As[64][72];   // +8 pad keeps 16B alignment (144B rows)
  __shared__ short Bs[64][72];
  A += (long)blockIdx.z * sA;
  Bt += (long)blockIdx.z * sB;
  const int m0 = blockIdx.x * 64;
  const int n0 = blockIdx.y * 64;
  const int t = threadIdx.x;
  const int wave = t >> 6, lane = t & 63;
  const int lrow = lane & 15, lq = lane >> 4;
  const int srow = t >> 2;          // 0..63
  const int scol = (t & 3) * 16;    // 0,16,32,48
  f32x4 acc[4] = {};
  const short* Ar = A + (long)(m0 + srow) * K + scol;
  const short* Br = Bt + (long)(n0 + srow) * K + scol;
  for (int k0 = 0; k0 < K; k0 += 64) {
    *(uint4*)&As[srow][scol]     = *(const uint4*)&Ar[k0];
    *(uint4*)&As[srow][scol + 8] = *(const uint4*)&Ar[k0 + 8];
    *(uint4*)&Bs[srow][scol]     = *(const uint4*)&Br[k0];
    *(uint4*)&Bs[srow][scol + 8] = *(const uint4*)&Br[k0 + 8];
    __syncthreads();
#pragma unroll
    for (int kk = 0; kk < 64; kk += 32) {
      bf16x8 a = *(bf16x8*)&As[wave * 16 + lrow][kk + lq * 8];
#pragma unroll
      for (int nt = 0; nt < 4; ++nt) {
        bf16x8 b = *(bf16x8*)&Bs[nt * 16 + lrow][kk + lq * 8];
        acc[nt] = __builtin_amdgcn_mfma_f32_16x16x32_bf16(a, b, acc[nt], 0, 0, 0);
      }
    }
    __syncthreads();
  }
  const long cbase = (long)blockIdx.z * sC;
#pragma unroll
  for (int nt = 0; nt < 4; ++nt) {
#pragma unroll
    for (int r = 0; r < 4; ++r) {
      const int row = m0 + wave * 16 + lq * 4 + r;  // C/D: row = quad*4+reg
      const int col = n0 + nt * 16 + lrow;          // C/D: col = lane&15
      float v = acc[nt][r] * scale;
      if (bias) v += bias[col];
      if (WRITE_BF16)
        ((short*)Cv)[cbase + (long)row * Nc + col] = f2bf(v);
      else
        ((float*)Cv)[cbase + (long)row * Nc + col] = v;
    }
  }
}

// ---------------------------------------------------------------------------
// sigsoftmax: in-place on fp32 scores rows (already * 1/sqrt(d));
// att = softmax(sigmoid(s)); also write bf16 copy. sigmoid in (0,1) => no
// max-subtraction needed for a stable softmax.
// ---------------------------------------------------------------------------
__global__ __launch_bounds__(256) void sigsoftmax(float* __restrict__ att,
                                                  short* __restrict__ attbf) {
  const long row = blockIdx.x;
  float* p = att + row * NN;
  const int t = threadIdx.x;
  float2 v = *(float2*)&p[t * 2];
  const float s0 = 1.f / (1.f + __expf(-v.x));
  const float s1 = 1.f / (1.f + __expf(-v.y));
  const float e0 = __expf(s0), e1 = __expf(s1);
  float sum = e0 + e1;
#pragma unroll
  for (int o = 32; o > 0; o >>= 1) sum += __shfl_down(sum, o);
  __shared__ float wsum[4];
  if ((t & 63) == 0) wsum[t >> 6] = sum;
  __syncthreads();
  const float r = 1.f / (wsum[0] + wsum[1] + wsum[2] + wsum[3]);
  const float a0 = e0 * r, a1 = e1 * r;
  float2 o2; o2.x = a0; o2.y = a1;
  *(float2*)&p[t * 2] = o2;
  short pk[2] = {f2bf(a0), f2bf(a1)};
  *(unsigned int*)&attbf[row * NN + t * 2] = *(unsigned int*)pk;
}

// out[b][j] = bm[j]  (atomicAdd target init; d_out is poisoned each launch)
__global__ __launch_bounds__(256) void init_out(float* __restrict__ out,
                                                const float* __restrict__ bm) {
  const int t = blockIdx.x * 256 + threadIdx.x;
  out[t] = bm[t & (HH - 1)];
}

// ---------------------------------------------------------------------------
// gemm_final: out[32][512] += out1_bf[32][262144] * Wm[262144][512]
// Split-K: gridDim.x chunks; Wm fp32 converted to bf16 during LDS staging
// (transposed to Bt layout). 4 waves: wave w owns 16 cols, both 16-row mtiles.
// ---------------------------------------------------------------------------
__global__ __launch_bounds__(256) void gemm_final(const short* __restrict__ A,
                                                  const float* __restrict__ Wm,
                                                  float* __restrict__ out) {
  __shared__ short As[32][40];
  __shared__ short Bs[64][40];
  const int j0 = blockIdx.y * 64;
  const long KT = (long)NN * HH;          // 262144
  const long Kc = KT / gridDim.x;
  const long i0base = (long)blockIdx.x * Kc;
  const int t = threadIdx.x;
  const int wave = t >> 6, lane = t & 63;
  const int lrow = lane & 15, lq = lane >> 4;
  const int jj = t & 63;
  const int rb = (t >> 6) * 8;
  f32x4 acc[2] = {};
  for (long i0 = i0base; i0 < i0base + Kc; i0 += 32) {
    if (t < 128) {
      const int ar = t >> 2;
      const int ac = (t & 3) * 8;
      *(uint4*)&As[ar][ac] = *(const uint4*)&A[(long)ar * KT + i0 + ac];
    }
#pragma unroll
    for (int r = 0; r < 8; ++r) {
      Bs[jj][rb + r] = f2bf(Wm[(i0 + rb + r) * HH + j0 + jj]);
    }
    __syncthreads();
    bf16x8 b  = *(bf16x8*)&Bs[wave * 16 + lrow][lq * 8];
    bf16x8 a0 = *(bf16x8*)&As[lrow][lq * 8];
    bf16x8 a1 = *(bf16x8*)&As[16 + lrow][lq * 8];
    acc[0] = __builtin_amdgcn_mfma_f32_16x16x32_bf16(a0, b, acc[0], 0, 0, 0);
    acc[1] = __builtin_amdgcn_mfma_f32_16x16x32_bf16(a1, b, acc[1], 0, 0, 0);
    __syncthreads();
  }
#pragma unroll
  for (int mt = 0; mt < 2; ++mt)
#pragma unroll
    for (int r = 0; r < 4; ++r) {
      const int brow = mt * 16 + lq * 4 + r;
      const int col = j0 + wave * 16 + lrow;
      atomicAdd(&out[(long)brow * HH + col], acc[mt][r]);
    }
}

extern "C" void kernel_launch(void* const* d_in, const int* in_sizes, int n_in,
                              void* d_out, int out_size, void* d_ws, size_t ws_size,
                              hipStream_t stream) {
  const float* x  = (const float*)d_in[0];
  const float* Wq = (const float*)d_in[1];
  const float* bq = (const float*)d_in[2];
  const float* Wk = (const float*)d_in[3];
  const float* bk = (const float*)d_in[4];
  const float* Wm = (const float*)d_in[5];
  const float* bm = (const float*)d_in[6];
  float* out = (float*)d_out;                 // [32*512]
  float* att = out + (long)BB * HH;           // [32*512*512] fp32

  char* ws = (char*)d_ws;
  const long SZ = (long)BB * NN * HH * sizeof(short);  // 16 MiB per buffer
  short* buf0 = (short*)ws;              // xbf, later reused as out1_bf
  short* buf1 = (short*)(ws + SZ);       // xT  [B][H][N]
  short* buf2 = (short*)(ws + 2 * SZ);   // q_bf, later reused as attn_bf
  short* buf3 = (short*)(ws + 3 * SZ);   // k_bf
  short* wqt  = (short*)(ws + 4 * SZ);   // WqT bf16 [D][H]
  short* wkt  = wqt + (long)HH * HH;     // WkT bf16 [D][H]

  prep_x<<<dim3(HH / 32, NN / 32, BB), 256, 0, stream>>>(x, buf0, buf1);
  prep_w<<<dim3(HH / 32, HH / 32, 2), 256, 0, stream>>>(Wq, Wk, wqt, wkt);

  // q = x @ Wq + bq ; k = x @ Wk + bk   (M = B*N)
  gemm_bt<1><<<dim3(BB * NN / 64, HH / 64, 1), 256, 0, stream>>>(
      buf0, wqt, buf2, bq, 1.f, BB * NN, HH, HH, 0, 0, 0);
  gemm_bt<1><<<dim3(BB * NN / 64, HH / 64, 1), 256, 0, stream>>>(
      buf0, wkt, buf3, bk, 1.f, BB * NN, HH, HH, 0, 0, 0);

  // scores[b] = q[b] @ k[b]^T / sqrt(d)  -> fp32 into attention output region
  gemm_bt<0><<<dim3(NN / 64, NN / 64, BB), 256, 0, stream>>>(
      buf2, buf3, att, nullptr, QK_SCALE, NN, NN, HH,
      (long)NN * HH, (long)NN * HH, (long)NN * NN);

  // attention = softmax(sigmoid(scores)) in-place (fp32) + bf16 copy in buf2
  sigsoftmax<<<dim3(BB * NN), 256, 0, stream>>>(att, buf2);

  // out1[b] = attn[b] @ x[b]  (Bt = xT[b])  -> bf16 into buf0
  gemm_bt<1><<<dim3(NN / 64, HH / 64, BB), 256, 0, stream>>>(
      buf2, buf1, buf0, nullptr, 1.f, NN, HH, NN,
      (long)NN * NN, (long)HH * NN, (long)NN * HH);

  // out = out1_flat @ Wm + bm  (split-K, atomic accumulate)
  init_out<<<dim3(BB * HH / 256), 256, 0, stream>>>(out, bm);
  gemm_final<<<dim3(256, HH / 64, 1), 256, 0, stream>>>(buf0, Wm, out);
}